// Round 3
// baseline (48231.070 us; speedup 1.0000x reference)
//
#include <hip/hip_runtime.h>
#include <math.h>

// GRU layer: B=64, T=512, I=512, H=1024, fp32.
// One launch per timestep (grid.sync flushes L2 every step: 17.9MB HBM
// writes/step, r1 rocprof — never again).
//
// r2 lesson: direct-global h reads + 512-thread blocks regressed 2x
// (VGPR-cap spills / exposed L3 latency). This round keeps r0's PROVEN
// 256-thread LDS-staged structure and adds latency hiding via:
//   * 2 blocks/CU (grid=512, JB=2): block-level TLP covers the
//     stage-barrier vmcnt drain of the sibling block.
//   * split-K x2 across the 4 waves: wave=(jloc,kh) consumes its 64-float
//     half of each staged 128-K chunk; LDS reduction at the end.
//   * register double-buffer (r1-proven): issue chunk c+1's 8 float4
//     loads right after the barrier; ONE barrier per chunk.

#define BB 64
#define TT 512
#define II 512
#define HH 1024
#define JB 2
#define CK 128
#define PAD 132   // 528B row stride: 16B-aligned; 2-way-per-quad bank pattern (free)

__device__ __forceinline__ void fma4(float4& a, const float4 xv, const float4 w) {
    a.x += xv.x * w.x;
    a.y += xv.y * w.y;
    a.z += xv.z * w.z;
    a.w += xv.w * w.w;
}

// Issue the 8 coalesced float4 loads of one 64x128 tile into registers.
__device__ __forceinline__ void issue_chunk(
    float4 (&st)[8], const float* __restrict__ base, size_t rowstride,
    int koff, int tid)
{
#pragma unroll
    for (int i = 0; i < 8; ++i) {
        int f   = tid + 256 * i;
        int row = f >> 5;           // 32 float4 per row
        int c4  = f & 31;
        st[i] = *(const float4*)(base + (size_t)row * rowstride + koff + c4 * 4);
    }
}

__global__ __launch_bounds__(256, 2) void gru_step(
    const float* __restrict__ x,
    const float* __restrict__ Wir, const float* __restrict__ Whr,
    const float* __restrict__ Wiz, const float* __restrict__ Whz,
    const float* __restrict__ Win, const float* __restrict__ Whn,
    const float* __restrict__ bir, const float* __restrict__ bhr,
    const float* __restrict__ biz, const float* __restrict__ bhz,
    const float* __restrict__ bin_, const float* __restrict__ bhn,
    float* __restrict__ out, int t)
{
    __shared__ float xs[2][BB][PAD];    // double-buffered 64x128 K-chunk
    __shared__ float red[JB][BB][4];    // split-K partials (kh=1 -> kh=0)

    const int tid  = threadIdx.x;
    const int b    = tid & 63;
    const int sel  = tid >> 6;           // wave id 0..3
    const int jloc = sel & 1;
    const int kh   = sel >> 1;           // K-half selector
    const int j    = __builtin_amdgcn_readfirstlane((int)blockIdx.x * JB + jloc);

    float4 aR  = {0.f, 0.f, 0.f, 0.f};
    float4 aZ  = {0.f, 0.f, 0.f, 0.f};
    float4 aXN = {0.f, 0.f, 0.f, 0.f};
    float4 aHN = {0.f, 0.f, 0.f, 0.f};

    const float* xbase = x   + (size_t)t * II;
    const float* hbase = out + (size_t)(t - 1) * HH;   // valid for t>0
    const int nch = (t > 0) ? 12 : 4;    // 4 x-chunks + 8 h-chunks

    float4 st[8];
    issue_chunk(st, xbase, (size_t)TT * II, 0, tid);   // prefetch chunk 0

    for (int c = 0; c < nch; ++c) {
        const int bufi = c & 1;
        // write previously-loaded registers to LDS
#pragma unroll
        for (int i = 0; i < 8; ++i) {
            const int f = tid + 256 * i;
            *(float4*)&xs[bufi][f >> 5][(f & 31) * 4] = st[i];
        }
        __syncthreads();
        // issue next chunk's loads; latency hides under accum + sibling block
        if (c + 1 < nch) {
            if (c + 1 < 4)
                issue_chunk(st, xbase, (size_t)TT * II, (c + 1) * CK, tid);
            else
                issue_chunk(st, hbase, (size_t)TT * HH, (c + 1 - 4) * CK, tid);
        }
        // accumulate this wave's 64-float half of the chunk
        {
            const float* xsrow = &xs[bufi][b][kh * 64];
            const float* wr; const float* wz; const float* wn;
            if (c < 4) {
                const size_t kw = (size_t)j * II + c * CK + kh * 64;
                wr = Wir + kw; wz = Wiz + kw; wn = Win + kw;
            } else {
                const size_t kw = (size_t)j * HH + (c - 4) * CK + kh * 64;
                wr = Whr + kw; wz = Whz + kw; wn = Whn + kw;
            }
            float4* aN = (c < 4) ? &aXN : &aHN;
#pragma unroll
            for (int k4 = 0; k4 < 16; ++k4) {
                float4 xv = *(const float4*)(xsrow + k4 * 4);
                fma4(aR,  xv, *(const float4*)(wr + k4 * 4));
                fma4(aZ,  xv, *(const float4*)(wz + k4 * 4));
                fma4(*aN, xv, *(const float4*)(wn + k4 * 4));
            }
        }
        // no trailing barrier: double buffer + next iteration's barrier
    }

    // ---------------- split-K reduction + epilogue -----------------------
    if (kh == 1) {
        red[jloc][b][0] = aR.x + aR.y + aR.z + aR.w;
        red[jloc][b][1] = aZ.x + aZ.y + aZ.z + aZ.w;
        red[jloc][b][2] = aXN.x + aXN.y + aXN.z + aXN.w;
        red[jloc][b][3] = aHN.x + aHN.y + aHN.z + aHN.w;
    }
    __syncthreads();
    if (kh == 0) {
        const float* r4 = &red[jloc][b][0];
        float rpre = (aR.x + aR.y + aR.z + aR.w) + r4[0] + bir[j] + bhr[j];
        float zpre = (aZ.x + aZ.y + aZ.z + aZ.w) + r4[1] + biz[j] + bhz[j];
        float xn   = (aXN.x + aXN.y + aXN.z + aXN.w) + r4[2] + bin_[j];
        float hn   = (aHN.x + aHN.y + aHN.z + aHN.w) + r4[3] + bhn[j];

        float r = 1.f / (1.f + __expf(-rpre));
        float z = 1.f / (1.f + __expf(-zpre));
        float n = tanhf(xn + r * hn);

        float hprev = (t > 0) ? out[(size_t)b * (TT * HH) + (size_t)(t - 1) * HH + j] : 0.f;
        out[(size_t)b * (TT * HH) + (size_t)t * HH + j] = (1.f - z) * n + z * hprev;
    }
}

extern "C" void kernel_launch(void* const* d_in, const int* in_sizes, int n_in,
                              void* d_out, int out_size, void* d_ws, size_t ws_size,
                              hipStream_t stream) {
    (void)in_sizes; (void)n_in; (void)d_ws; (void)ws_size; (void)out_size;

    const float* x    = (const float*)d_in[0];
    const float* Wir  = (const float*)d_in[1];
    const float* bir  = (const float*)d_in[2];
    const float* Whr  = (const float*)d_in[3];
    const float* bhr  = (const float*)d_in[4];
    const float* Wiz  = (const float*)d_in[5];
    const float* biz  = (const float*)d_in[6];
    const float* Whz  = (const float*)d_in[7];
    const float* bhz  = (const float*)d_in[8];
    const float* Win  = (const float*)d_in[9];
    const float* bin_ = (const float*)d_in[10];
    const float* Whn  = (const float*)d_in[11];
    const float* bhn  = (const float*)d_in[12];
    float* out = (float*)d_out;

    for (int t = 0; t < TT; ++t) {
        gru_step<<<dim3(HH / JB), dim3(256), 0, stream>>>(
            x, Wir, Whr, Wiz, Whz, Win, Whn,
            bir, bhr, biz, bhz, bin_, bhn, out, t);
    }
}

// Round 4
// 34185.388 us; speedup vs baseline: 1.4109x; 1.4109x over previous
//
#include <hip/hip_runtime.h>
#include <math.h>

// GRU layer: B=64, T=512, I=512, H=1024, fp32.
// One launch per timestep; h-history lives in d_out (out[b][t][:] == h_t).
// r0-proven structure: grid=256 (1 block/CU), 256 threads, JB=4 hidden j
// per block (one j per wave), K-loop over 1536 in CK=128 LDS-staged chunks.
//
// r4 change (ONE variable vs r0): single-barrier register double-buffer.
//   prologue: issue chunk 0's 8 float4 loads into registers.
//   loop c:   ds_write regs -> xs[c&1]; __syncthreads();
//             issue chunk c+1's loads (L3 latency hides under accum);
//             accumulate chunk c from xs[c&1]. No trailing barrier
//             (double buffer + next iteration's barrier protect reuse).
// Also: bias scalar loads + hprev global load issued at kernel start
// (they were latency-exposed at the tail in r0).
//
// Lessons kept: grid must stay 256 blocks (512 blocks doubles broadcast
// staging traffic — r3); no VGPR cap (spills killed r2); PAD=132 layout
// is bank-conflict-free (r1 rocprof: SQ_LDS_BANK_CONFLICT=0).

#define BB 64
#define TT 512
#define II 512
#define HH 1024
#define JB 4
#define CK 128
#define PAD 132   // 528B row stride: 16B-aligned, balanced LDS banks

__device__ __forceinline__ void fma4(float4& a, const float4 xv, const float4 w) {
    a.x += xv.x * w.x;
    a.y += xv.y * w.y;
    a.z += xv.z * w.z;
    a.w += xv.w * w.w;
}

// Issue the 8 coalesced float4 loads of one 64x128 tile into registers.
__device__ __forceinline__ void issue_chunk(
    float4 (&st)[8], const float* __restrict__ base, size_t rowstride,
    int koff, int tid)
{
#pragma unroll
    for (int i = 0; i < 8; ++i) {
        int f   = tid + 256 * i;
        int row = f >> 5;           // 32 float4 per row
        int c4  = f & 31;
        st[i] = *(const float4*)(base + (size_t)row * rowstride + koff + c4 * 4);
    }
}

__global__ __launch_bounds__(256) void gru_step(
    const float* __restrict__ x,
    const float* __restrict__ Wir, const float* __restrict__ Whr,
    const float* __restrict__ Wiz, const float* __restrict__ Whz,
    const float* __restrict__ Win, const float* __restrict__ Whn,
    const float* __restrict__ bir, const float* __restrict__ bhr,
    const float* __restrict__ biz, const float* __restrict__ bhz,
    const float* __restrict__ bin_, const float* __restrict__ bhn,
    float* __restrict__ out, int t)
{
    __shared__ float xs[2][BB][PAD];    // double-buffered 64x128 K-chunk
    const int tid = threadIdx.x;
    const int b   = tid & 63;
    const int jg  = tid >> 6;                      // 0..3, wave-uniform
    const int j   = __builtin_amdgcn_readfirstlane((int)blockIdx.x * JB + jg);

    // early: bias scalar loads + hprev (value used only at the tail)
    const float bir_j = bir[j], bhr_j = bhr[j];
    const float biz_j = biz[j], bhz_j = bhz[j];
    const float bin_j = bin_[j], bhn_j = bhn[j];
    float hprev = 0.f;
    if (t > 0)
        hprev = out[(size_t)b * (TT * HH) + (size_t)(t - 1) * HH + j];

    float4 aR  = {0.f, 0.f, 0.f, 0.f};
    float4 aZ  = {0.f, 0.f, 0.f, 0.f};
    float4 aXN = {0.f, 0.f, 0.f, 0.f};
    float4 aHN = {0.f, 0.f, 0.f, 0.f};

    const float* xbase = x   + (size_t)t * II;
    const float* hbase = out + (size_t)(t - 1) * HH;   // valid for t>0
    const int nch = (t > 0) ? 12 : 4;    // 4 x-chunks + 8 h-chunks

    float4 st[8];
    issue_chunk(st, xbase, (size_t)TT * II, 0, tid);   // prefetch chunk 0

    for (int c = 0; c < nch; ++c) {
        const int bufi = c & 1;
        // write previously-loaded registers to LDS
#pragma unroll
        for (int i = 0; i < 8; ++i) {
            const int f = tid + 256 * i;
            *(float4*)&xs[bufi][f >> 5][(f & 31) * 4] = st[i];
        }
        __syncthreads();
        // issue next chunk's loads; latency hides under accum below
        if (c + 1 < nch) {
            if (c + 1 < 4)
                issue_chunk(st, xbase, (size_t)TT * II, (c + 1) * CK, tid);
            else
                issue_chunk(st, hbase, (size_t)TT * HH, (c + 1 - 4) * CK, tid);
        }
        // accumulate chunk c (full 128-K width, 3 gates, same order as r0)
        {
            const float* xsrow = &xs[bufi][b][0];
            const float* wr; const float* wz; const float* wn;
            float4* aN;
            if (c < 4) {
                const size_t kw = (size_t)j * II + c * CK;
                wr = Wir + kw; wz = Wiz + kw; wn = Win + kw;
                aN = &aXN;
            } else {
                const size_t kw = (size_t)j * HH + (c - 4) * CK;
                wr = Whr + kw; wz = Whz + kw; wn = Whn + kw;
                aN = &aHN;
            }
#pragma unroll
            for (int k4 = 0; k4 < CK / 4; ++k4) {
                float4 xv = *(const float4*)(xsrow + k4 * 4);
                fma4(aR,  xv, *(const float4*)(wr + k4 * 4));
                fma4(aZ,  xv, *(const float4*)(wz + k4 * 4));
                fma4(*aN, xv, *(const float4*)(wn + k4 * 4));
            }
        }
        // no trailing barrier: double buffer + next iteration's barrier
    }

    // ---------- epilogue: gates + state update (same order as r0) --------
    float rpre = (aR.x + aR.y + aR.z + aR.w) + bir_j + bhr_j;
    float zpre = (aZ.x + aZ.y + aZ.z + aZ.w) + biz_j + bhz_j;
    float hn   = (aHN.x + aHN.y + aHN.z + aHN.w) + bhn_j;
    float xn   = (aXN.x + aXN.y + aXN.z + aXN.w) + bin_j;

    float r = 1.f / (1.f + __expf(-rpre));
    float z = 1.f / (1.f + __expf(-zpre));
    float n = tanhf(xn + r * hn);

    float hnew = (1.f - z) * n + z * hprev;
    out[(size_t)b * (TT * HH) + (size_t)t * HH + j] = hnew;
}

extern "C" void kernel_launch(void* const* d_in, const int* in_sizes, int n_in,
                              void* d_out, int out_size, void* d_ws, size_t ws_size,
                              hipStream_t stream) {
    (void)in_sizes; (void)n_in; (void)d_ws; (void)ws_size; (void)out_size;

    const float* x    = (const float*)d_in[0];
    const float* Wir  = (const float*)d_in[1];
    const float* bir  = (const float*)d_in[2];
    const float* Whr  = (const float*)d_in[3];
    const float* bhr  = (const float*)d_in[4];
    const float* Wiz  = (const float*)d_in[5];
    const float* biz  = (const float*)d_in[6];
    const float* Whz  = (const float*)d_in[7];
    const float* bhz  = (const float*)d_in[8];
    const float* Win  = (const float*)d_in[9];
    const float* bin_ = (const float*)d_in[10];
    const float* Whn  = (const float*)d_in[11];
    const float* bhn  = (const float*)d_in[12];
    float* out = (float*)d_out;

    for (int t = 0; t < TT; ++t) {
        gru_step<<<dim3(HH / JB), dim3(256), 0, stream>>>(
            x, Wir, Whr, Wiz, Whz, Win, Whn,
            bir, bhr, biz, bhz, bin_, bhn, out, t);
    }
}

// Round 5
// 15862.248 us; speedup vs baseline: 3.0406x; 2.1551x over previous
//
#include <hip/hip_runtime.h>
#include <math.h>

// GRU layer: B=64, T=512, I=512, H=1024, fp32.
//
// r4 lesson: `(cond) ? &accA : &accB` demotes accumulators to scratch
// (34ms). r2/r3 similar (VGPR cap / same pointer select). All scheduling
// "improvements" were confounded by accumulator demotion. r0's statically
// bound accumulators + two-barrier staging = the only proven inner loop.
//
// This round: hoist the x-projection out of the serial t-loop.
//   Phase 1 (xproj, one launch, 32768 blocks): xpre[g][t][j][b] =
//     dot(x[b][t][:], W_i_g[j][:])  — 103 GFLOP parallel GEMM, ~1ms.
//   Phase 2 (gru_step_h, 512 launches): h-part only, 8 chunks of K=128
//     staged in LDS exactly like r0 (single buffer, two barriers), plus
//     3 coalesced xpre reads. 33% less serial work, no x staging.
// Fallback: if ws_size < 402MB, run r0 verbatim (gru_step_full).

#define BB 64
#define TT 512
#define II 512
#define HH 1024
#define JB 4
#define CK 128
#define PAD 132   // 528B row stride: 16B-aligned; bank-conflict-free (r1 PMC)
#define XJ 16     // hidden-j per block in xproj (4 per wave)

__device__ __forceinline__ void fma4(float4& a, const float4 xv, const float4 w) {
    a.x += xv.x * w.x;
    a.y += xv.y * w.y;
    a.z += xv.z * w.z;
    a.w += xv.w * w.w;
}

// ---------------------------------------------------------------------------
// Phase 1: x-projections for all t. grid = TT*64 blocks, 256 threads.
// block -> (t = bid>>6, jgrp = bid&63); wave w owns j0 = jgrp*16 + w*4 .. +3.
// ---------------------------------------------------------------------------
__global__ __launch_bounds__(256) void xproj(
    const float* __restrict__ x,
    const float* __restrict__ Wir, const float* __restrict__ Wiz,
    const float* __restrict__ Win, float* __restrict__ xpre)
{
    __shared__ float xs[BB][PAD];
    const int tid  = threadIdx.x;
    const int b    = tid & 63;
    const int w    = tid >> 6;
    const int bid  = (int)blockIdx.x;
    const int t    = bid >> 6;
    const int jgrp = bid & 63;
    const int j0   = __builtin_amdgcn_readfirstlane(jgrp * XJ + w * 4);

    float4 acc[4][3];
#pragma unroll
    for (int jj = 0; jj < 4; ++jj)
#pragma unroll
        for (int g = 0; g < 3; ++g)
            acc[jj][g] = {0.f, 0.f, 0.f, 0.f};

    const float* xbase = x + (size_t)t * II;
    for (int kc = 0; kc < II / CK; ++kc) {
#pragma unroll
        for (int i = 0; i < 8; ++i) {
            int f   = tid + 256 * i;
            int row = f >> 5;
            int c4  = f & 31;
            *(float4*)&xs[row][c4 * 4] =
                *(const float4*)(xbase + (size_t)row * (TT * II) + kc * CK + c4 * 4);
        }
        __syncthreads();
        const float* xsrow = &xs[b][0];
#pragma unroll
        for (int k4 = 0; k4 < CK / 4; ++k4) {
            float4 xv = *(const float4*)(xsrow + k4 * 4);
#pragma unroll
            for (int jj = 0; jj < 4; ++jj) {
                const size_t wof = (size_t)(j0 + jj) * II + kc * CK + k4 * 4;
                fma4(acc[jj][0], xv, *(const float4*)(Wir + wof));
                fma4(acc[jj][1], xv, *(const float4*)(Wiz + wof));
                fma4(acc[jj][2], xv, *(const float4*)(Win + wof));
            }
        }
        __syncthreads();
    }

#pragma unroll
    for (int jj = 0; jj < 4; ++jj) {
        const int j = j0 + jj;
#pragma unroll
        for (int g = 0; g < 3; ++g) {
            float s = acc[jj][g].x + acc[jj][g].y + acc[jj][g].z + acc[jj][g].w;
            xpre[(((size_t)g * TT + t) * HH + j) * BB + b] = s;
        }
    }
}

// ---------------------------------------------------------------------------
// Phase 2: recurrent step, h-part only. grid = 256, 256 threads (r0 shape).
// ---------------------------------------------------------------------------
__global__ __launch_bounds__(256) void gru_step_h(
    const float* __restrict__ Whr, const float* __restrict__ Whz,
    const float* __restrict__ Whn,
    const float* __restrict__ bir, const float* __restrict__ bhr,
    const float* __restrict__ biz, const float* __restrict__ bhz,
    const float* __restrict__ bin_, const float* __restrict__ bhn,
    const float* __restrict__ xpre,
    float* __restrict__ out, int t)
{
    __shared__ float xs[BB][PAD];
    const int tid = threadIdx.x;
    const int b   = tid & 63;
    const int jg  = tid >> 6;
    const int j   = __builtin_amdgcn_readfirstlane((int)blockIdx.x * JB + jg);

    const float bir_j = bir[j], bhr_j = bhr[j];
    const float biz_j = biz[j], bhz_j = bhz[j];
    const float bin_j = bin_[j], bhn_j = bhn[j];
    const float xr  = xpre[(((size_t)0 * TT + t) * HH + j) * BB + b];
    const float xz  = xpre[(((size_t)1 * TT + t) * HH + j) * BB + b];
    const float xn0 = xpre[(((size_t)2 * TT + t) * HH + j) * BB + b];
    float hprev = 0.f;
    if (t > 0)
        hprev = out[(size_t)b * (TT * HH) + (size_t)(t - 1) * HH + j];

    float4 aR  = {0.f, 0.f, 0.f, 0.f};
    float4 aZ  = {0.f, 0.f, 0.f, 0.f};
    float4 aHN = {0.f, 0.f, 0.f, 0.f};

    if (t > 0) {
        const float* hbase = out + (size_t)(t - 1) * HH;
        for (int kc = 0; kc < HH / CK; ++kc) {
#pragma unroll
            for (int i = 0; i < 8; ++i) {
                int f   = tid + 256 * i;
                int row = f >> 5;
                int c4  = f & 31;
                *(float4*)&xs[row][c4 * 4] =
                    *(const float4*)(hbase + (size_t)row * (TT * HH) + kc * CK + c4 * 4);
            }
            __syncthreads();
            const float* xsrow = &xs[b][0];
            const float* wr = Whr + (size_t)j * HH + kc * CK;
            const float* wz = Whz + (size_t)j * HH + kc * CK;
            const float* wn = Whn + (size_t)j * HH + kc * CK;
#pragma unroll
            for (int k4 = 0; k4 < CK / 4; ++k4) {
                float4 xv = *(const float4*)(xsrow + k4 * 4);
                fma4(aR,  xv, *(const float4*)(wr + k4 * 4));
                fma4(aZ,  xv, *(const float4*)(wz + k4 * 4));
                fma4(aHN, xv, *(const float4*)(wn + k4 * 4));
            }
            __syncthreads();
        }
    }

    float rpre = (aR.x + aR.y + aR.z + aR.w) + xr + bir_j + bhr_j;
    float zpre = (aZ.x + aZ.y + aZ.z + aZ.w) + xz + biz_j + bhz_j;
    float hn   = (aHN.x + aHN.y + aHN.z + aHN.w) + bhn_j;
    float xn   = xn0 + bin_j;

    float r = 1.f / (1.f + __expf(-rpre));
    float z = 1.f / (1.f + __expf(-zpre));
    float n = tanhf(xn + r * hn);

    out[(size_t)b * (TT * HH) + (size_t)t * HH + j] = (1.f - z) * n + z * hprev;
}

// ---------------------------------------------------------------------------
// Fallback: r0 kernel verbatim (measured 14129 us) for small ws_size.
// ---------------------------------------------------------------------------
__device__ __forceinline__ void accum_chunk(
    const float* __restrict__ xsrow,
    const float* __restrict__ wr, const float* __restrict__ wz,
    const float* __restrict__ wn,
    float4& aR, float4& aZ, float4& aN)
{
#pragma unroll
    for (int k4 = 0; k4 < CK / 4; ++k4) {
        float4 xv = *(const float4*)(xsrow + k4 * 4);
        fma4(aR, xv, *(const float4*)(wr + k4 * 4));
        fma4(aZ, xv, *(const float4*)(wz + k4 * 4));
        fma4(aN, xv, *(const float4*)(wn + k4 * 4));
    }
}

__global__ __launch_bounds__(256) void gru_step_full(
    const float* __restrict__ x,
    const float* __restrict__ Wir, const float* __restrict__ Whr,
    const float* __restrict__ Wiz, const float* __restrict__ Whz,
    const float* __restrict__ Win, const float* __restrict__ Whn,
    const float* __restrict__ bir, const float* __restrict__ bhr,
    const float* __restrict__ biz, const float* __restrict__ bhz,
    const float* __restrict__ bin_, const float* __restrict__ bhn,
    float* __restrict__ out, int t)
{
    __shared__ float xs[BB][PAD];
    const int tid = threadIdx.x;
    const int b   = tid & 63;
    const int jg  = tid >> 6;
    const int j   = __builtin_amdgcn_readfirstlane((int)blockIdx.x * JB + jg);

    float4 aR  = {0.f, 0.f, 0.f, 0.f};
    float4 aZ  = {0.f, 0.f, 0.f, 0.f};
    float4 aXN = {0.f, 0.f, 0.f, 0.f};
    float4 aHN = {0.f, 0.f, 0.f, 0.f};

    const float* xbase = x + (size_t)t * II;
    for (int kc = 0; kc < II / CK; ++kc) {
#pragma unroll
        for (int i = 0; i < 8; ++i) {
            int f   = tid + 256 * i;
            int row = f >> 5;
            int c4  = f & 31;
            *(float4*)&xs[row][c4 * 4] =
                *(const float4*)(xbase + (size_t)row * (TT * II) + kc * CK + c4 * 4);
        }
        __syncthreads();
        accum_chunk(&xs[b][0],
                    Wir + (size_t)j * II + kc * CK,
                    Wiz + (size_t)j * II + kc * CK,
                    Win + (size_t)j * II + kc * CK,
                    aR, aZ, aXN);
        __syncthreads();
    }

    if (t > 0) {
        const float* hbase = out + (size_t)(t - 1) * HH;
        for (int kc = 0; kc < HH / CK; ++kc) {
#pragma unroll
            for (int i = 0; i < 8; ++i) {
                int f   = tid + 256 * i;
                int row = f >> 5;
                int c4  = f & 31;
                *(float4*)&xs[row][c4 * 4] =
                    *(const float4*)(hbase + (size_t)row * (TT * HH) + kc * CK + c4 * 4);
            }
            __syncthreads();
            accum_chunk(&xs[b][0],
                        Whr + (size_t)j * HH + kc * CK,
                        Whz + (size_t)j * HH + kc * CK,
                        Whn + (size_t)j * HH + kc * CK,
                        aR, aZ, aHN);
            __syncthreads();
        }
    }

    float rpre = (aR.x + aR.y + aR.z + aR.w) + bir[j] + bhr[j];
    float zpre = (aZ.x + aZ.y + aZ.z + aZ.w) + biz[j] + bhz[j];
    float hn   = (aHN.x + aHN.y + aHN.z + aHN.w) + bhn[j];
    float xn   = (aXN.x + aXN.y + aXN.z + aXN.w) + bin_[j];

    float r = 1.f / (1.f + __expf(-rpre));
    float z = 1.f / (1.f + __expf(-zpre));
    float n = tanhf(xn + r * hn);

    float hprev = (t > 0) ? out[(size_t)b * (TT * HH) + (size_t)(t - 1) * HH + j] : 0.f;
    out[(size_t)b * (TT * HH) + (size_t)t * HH + j] = (1.f - z) * n + z * hprev;
}

extern "C" void kernel_launch(void* const* d_in, const int* in_sizes, int n_in,
                              void* d_out, int out_size, void* d_ws, size_t ws_size,
                              hipStream_t stream) {
    (void)in_sizes; (void)n_in; (void)out_size;

    const float* x    = (const float*)d_in[0];
    const float* Wir  = (const float*)d_in[1];
    const float* bir  = (const float*)d_in[2];
    const float* Whr  = (const float*)d_in[3];
    const float* bhr  = (const float*)d_in[4];
    const float* Wiz  = (const float*)d_in[5];
    const float* biz  = (const float*)d_in[6];
    const float* Whz  = (const float*)d_in[7];
    const float* bhz  = (const float*)d_in[8];
    const float* Win  = (const float*)d_in[9];
    const float* bin_ = (const float*)d_in[10];
    const float* Whn  = (const float*)d_in[11];
    const float* bhn  = (const float*)d_in[12];
    float* out = (float*)d_out;

    const size_t need = (size_t)3 * TT * HH * BB * sizeof(float);  // 402.6 MB
    if (d_ws != nullptr && ws_size >= need) {
        float* xpre = (float*)d_ws;
        xproj<<<dim3(TT * 64), dim3(256), 0, stream>>>(x, Wir, Wiz, Win, xpre);
        for (int t = 0; t < TT; ++t) {
            gru_step_h<<<dim3(HH / JB), dim3(256), 0, stream>>>(
                Whr, Whz, Whn, bir, bhr, biz, bhz, bin_, bhn, xpre, out, t);
        }
    } else {
        for (int t = 0; t < TT; ++t) {
            gru_step_full<<<dim3(HH / JB), dim3(256), 0, stream>>>(
                x, Wir, Whr, Wiz, Whz, Win, Whn,
                bir, bhr, biz, bhz, bin_, bhn, out, t);
        }
    }
}